// Round 2
// baseline (203.859 us; speedup 1.0000x reference)
//
#include <hip/hip_runtime.h>

#define B_DIM 64
#define T_DIM 524288
#define D_FAC 16
#define NF 32768         // frames per row (T/D)
#define LBLK 64          // frames per composed block
#define NB 512           // blocks per row
#define NCLS 65          // LBLK+1 slope classes
#define EPSV 1e-7f
#define BIGC 1e30f

// 20*log10(2)
#define DB_PER_LOG2 6.0205999132796239f
// log2(10)/20
#define L2TEN_OVER20 0.16609640474436813f

__device__ __forceinline__ float sum_log2_4(float4 x) {
  return __log2f(fabsf(x.x) + EPSV) + __log2f(fabsf(x.y) + EPSV) +
         __log2f(fabsf(x.z) + EPSV) + __log2f(fabsf(x.w) + EPSV);
}

template <int CTRL, int RM>
__device__ __forceinline__ float fmin_dpp_step(float v) {
  int vi = __float_as_int(v);
  int sh = __builtin_amdgcn_update_dpp(vi, vi, CTRL, RM, 0xf, false);
  return fminf(v, __int_as_float(sh));
}

// K1: per-frame gain g, then compose each 64-frame block into 65 affine-min
// constants. One WG = 256 threads covers 4096 frames (= 64 blocks, 256 KB audio).
__global__ __launch_bounds__(256) void k1_compose(
    const float* __restrict__ audio, const float* __restrict__ p_thr,
    const float* __restrict__ p_ratio, const float* __restrict__ p_att,
    const float* __restrict__ p_rel, float* __restrict__ consts) {
  __shared__ float gl[4096 + 128];  // pad 1 float per 32
  const int tid = threadIdx.x;
  const int wg = blockIdx.x;  // 0..511
  const int row = wg >> 3;
  const int seg = wg & 7;  // 4096-frame segment within row
  const float thr = p_thr[0];
  const float ratio = p_ratio[0];
  const float A = p_att[0], R = p_rel[0];
  const float oneA = 1.f - A, oneR = 1.f - R;
  const float gslope = (1.f / ratio) - 1.f;  // negative for ratio>1
  const size_t abase = (size_t)row * T_DIM + (size_t)seg * (4096 * D_FAC);

  // Step A: per-frame g into LDS (coalesced: lane reads 64B of its frame)
  for (int j = 0; j < 16; ++j) {
    int f = j * 256 + tid;  // local frame 0..4095
    const float4* ap = (const float4*)(audio + abase + (size_t)f * D_FAC);
    float s = 0.f;
#pragma unroll
    for (int q = 0; q < 4; ++q) s += sum_log2_4(ap[q]);
    float xdb = s * (DB_PER_LOG2 / 16.f);
    float g = fminf(0.f, (xdb - thr) * gslope);
    gl[f + (f >> 5)] = g;
  }
  __syncthreads();
  if (tid >= 64) return;

  // Step B: lane tid composes block tid. c[a] = min constant for slope A^a R^(t-a).
  float c[NCLS];
  c[0] = 0.f;
#pragma unroll
  for (int a = 1; a < NCLS; ++a) c[a] = BIGC;
  const int ebase = tid * LBLK;
  for (int t = 0; t < LBLK; ++t) {
    int e = ebase + t;
    float gt = gl[e + (e >> 5)];
    float ca = oneA * gt, cr = oneR * gt;
#pragma unroll
    for (int a = NCLS - 1; a >= 1; --a)
      c[a] = fminf(fmaf(A, c[a - 1], ca), fmaf(R, c[a], cr));
    c[0] = fmaf(R, c[0], cr);
  }
  float* outp = consts + (size_t)(row * NB + seg * 64 + tid) * NCLS;
#pragma unroll
  for (int a = 0; a < NCLS; ++a) outp[a] = c[a];
}

// K2: serial scan over 512 blocks per row. One wave per row; lane a holds
// slope class a (lane 63 also handles class 64). DPP min-reduce per step.
__global__ __launch_bounds__(64) void k2_scan(const float* __restrict__ consts,
                                              float* __restrict__ states,
                                              const float* __restrict__ p_att,
                                              const float* __restrict__ p_rel) {
  const int r = blockIdx.x;
  const int lane = threadIdx.x;
  const float A = p_att[0], R = p_rel[0];
  float s = 1.f, sA = 1.f;
  for (int i = 0; i < 64; ++i) {
    s *= (i < lane) ? A : R;  // s = A^lane * R^(64-lane)
    sA *= A;                  // A^64
  }
  const bool last = (lane == 63);
  const float s2 = last ? sA : s;
  const int off1 = lane;
  const int off2 = last ? 64 : lane;
  const float* base = consts + (size_t)r * NB * NCLS;
  float* st = states + r * NB;
  float p = 0.f;

  float cb[8], eb[8];
#pragma unroll
  for (int j = 0; j < 8; ++j) {
    cb[j] = base[j * NCLS + off1];
    eb[j] = base[j * NCLS + off2];
  }
  for (int bb = 0; bb < NB; bb += 8) {
#pragma unroll
    for (int j = 0; j < 8; ++j) {
      int b = bb + j;
      float v = fminf(fmaf(s, p, cb[j]), fmaf(s2, p, eb[j]));
      v = fmin_dpp_step<0x111, 0xf>(v);  // row_shr:1
      v = fmin_dpp_step<0x112, 0xf>(v);  // row_shr:2
      v = fmin_dpp_step<0x114, 0xf>(v);  // row_shr:4
      v = fmin_dpp_step<0x118, 0xf>(v);  // row_shr:8
      v = fmin_dpp_step<0x142, 0xa>(v);  // row_bcast:15 -> rows 1,3
      v = fmin_dpp_step<0x143, 0xc>(v);  // row_bcast:31 -> rows 2,3
      float pn = __int_as_float(__builtin_amdgcn_readlane(__float_as_int(v), 63));
      if (lane == 0) st[b] = p;  // state at START of block b
      p = pn;
      int nb2 = b + 8;
      if (nb2 < NB) {
        cb[j] = base[nb2 * NCLS + off1];
        eb[j] = base[nb2 * NCLS + off2];
      }
    }
  }
}

// K3: one wave per block. Each lane owns one frame (16 samples in regs),
// wave re-runs the 64-step recurrence from the block-start state via
// readlane broadcasts, then applies gain.
__global__ __launch_bounds__(256) void k3_apply(
    const float* __restrict__ audio, const float* __restrict__ states,
    const float* __restrict__ p_thr, const float* __restrict__ p_ratio,
    const float* __restrict__ p_makeup, const float* __restrict__ p_att,
    const float* __restrict__ p_rel, float* __restrict__ out) {
  const int tid = threadIdx.x;
  const int lane = tid & 63;
  const int w = tid >> 6;
  const int gblk = blockIdx.x * 4 + w;  // 0..32767
  const int row = gblk >> 9;
  const int b = gblk & (NB - 1);
  const float thr = p_thr[0], ratio = p_ratio[0], mk = p_makeup[0];
  const float A = p_att[0], R = p_rel[0];
  const float oneA = 1.f - A, oneR = 1.f - R;
  const float gslope = (1.f / ratio) - 1.f;

  const size_t sbase = (size_t)row * T_DIM + (size_t)(b * LBLK + lane) * D_FAC;
  const float4* ap = (const float4*)(audio + sbase);
  float4 x0 = ap[0], x1 = ap[1], x2 = ap[2], x3 = ap[3];
  float s = sum_log2_4(x0) + sum_log2_4(x1) + sum_log2_4(x2) + sum_log2_4(x3);
  float xdb = s * (DB_PER_LOG2 / 16.f);
  float g = fminf(0.f, (xdb - thr) * gslope);

  float p = states[gblk];
  float m = 0.f;
  int gi = __float_as_int(g);
#pragma unroll
  for (int t = 0; t < LBLK; ++t) {
    float gt = __int_as_float(__builtin_amdgcn_readlane(gi, t));
    p = fminf(fmaf(A, p, oneA * gt), fmaf(R, p, oneR * gt));
    m = (lane == t) ? p : m;
  }
  float mult = exp2f((m + mk) * L2TEN_OVER20);
  float4* op = (float4*)(out + sbase);
  float4 y0, y1, y2, y3;
  y0.x = x0.x * mult; y0.y = x0.y * mult; y0.z = x0.z * mult; y0.w = x0.w * mult;
  y1.x = x1.x * mult; y1.y = x1.y * mult; y1.z = x1.z * mult; y1.w = x1.w * mult;
  y2.x = x2.x * mult; y2.y = x2.y * mult; y2.z = x2.z * mult; y2.w = x2.w * mult;
  y3.x = x3.x * mult; y3.y = x3.y * mult; y3.z = x3.z * mult; y3.w = x3.w * mult;
  op[0] = y0; op[1] = y1; op[2] = y2; op[3] = y3;
}

extern "C" void kernel_launch(void* const* d_in, const int* in_sizes, int n_in,
                              void* d_out, int out_size, void* d_ws,
                              size_t ws_size, hipStream_t stream) {
  const float* audio = (const float*)d_in[0];
  const float* thr = (const float*)d_in[1];
  const float* ratio = (const float*)d_in[2];
  const float* makeup = (const float*)d_in[3];
  const float* att = (const float*)d_in[4];
  const float* rel = (const float*)d_in[5];
  float* out = (float*)d_out;

  const size_t CONSTS_BYTES = (size_t)B_DIM * NB * NCLS * sizeof(float);  // ~8.5 MB
  const size_t STATES_BYTES = (size_t)B_DIM * NB * sizeof(float);         // 128 KB

  float* consts;
  float* states;
  if (ws_size >= CONSTS_BYTES + STATES_BYTES) {
    consts = (float*)d_ws;
    states = (float*)((char*)d_ws + CONSTS_BYTES);
  } else {
    // d_out (128 MB) as scratch for consts: only live during K1->K2, and K3
    // overwrites every byte of d_out afterwards. states (128 KB) stays in ws.
    consts = (float*)d_out;
    states = (float*)d_ws;
  }

  hipLaunchKernelGGL(k1_compose, dim3(512), dim3(256), 0, stream, audio, thr,
                     ratio, att, rel, consts);
  hipLaunchKernelGGL(k2_scan, dim3(64), dim3(64), 0, stream, consts, states,
                     att, rel);
  hipLaunchKernelGGL(k3_apply, dim3(8192), dim3(256), 0, stream, audio, states,
                     thr, ratio, makeup, att, rel, out);
}